// Round 2
// baseline (867.183 us; speedup 1.0000x reference)
//
#include <hip/hip_runtime.h>
#include <hip/hip_bf16.h>

// ---------------- types / helpers ----------------
typedef __attribute__((ext_vector_type(8))) short bf16x8;
typedef __attribute__((ext_vector_type(4))) float f32x4;

#define T_TOK 2048
#define HD 1024
#define ID 512
#define NE 16
#define TOPK 4
#define TM 32   // tokens per expert tile

// pack two fp32 -> two bf16 (truncate), low short = bf16(a): one v_perm_b32
__device__ __forceinline__ unsigned pk2(float a, float b) {
    return __builtin_amdgcn_perm(__float_as_uint(b), __float_as_uint(a),
                                 0x07060302u);
}
// load 8 fp32 and convert to bf16x8 (two dwordx4 loads + 4 v_perm)
__device__ __forceinline__ bf16x8 cvt8(const float* __restrict__ p) {
    float4 a = *(const float4*)p;
    float4 b = *(const float4*)(p + 4);
    union { bf16x8 v; unsigned u[4]; } r;
    r.u[0] = pk2(a.x, a.y); r.u[1] = pk2(a.z, a.w);
    r.u[2] = pk2(b.x, b.y); r.u[3] = pk2(b.z, b.w);
    return r.v;
}
__device__ __forceinline__ short f2bf(float f) {  // RTNE, epilogue only
    unsigned u = __float_as_uint(f);
    return (short)((u + 0x7fffu + ((u >> 16) & 1u)) >> 16);
}

#define MFMA_BF16 __builtin_amdgcn_mfma_f32_16x16x32_bf16

// ---------------- kernel 1: router (fp32 in) ----------------
__global__ __launch_bounds__(256) void router_k(
        const float* __restrict__ x, const float* __restrict__ gw,
        const float* __restrict__ eb,
        int* __restrict__ tk_idx, float* __restrict__ tk_w) {
    int wid  = (blockIdx.x * 256 + threadIdx.x) >> 6;   // token id
    int lane = threadIdx.x & 63;

    const float* xr = x + (size_t)wid * HD + lane * 16;
    float xv[16];
#pragma unroll
    for (int c = 0; c < 4; c++) {
        float4 v = *(const float4*)(xr + c * 4);
        xv[4 * c] = v.x; xv[4 * c + 1] = v.y; xv[4 * c + 2] = v.z; xv[4 * c + 3] = v.w;
    }

    float logits[NE];
#pragma unroll
    for (int e = 0; e < NE; e++) {
        const float* gr = gw + e * HD + lane * 16;
        float p = 0.f;
#pragma unroll
        for (int c = 0; c < 4; c++) {
            float4 v = *(const float4*)(gr + c * 4);
            p += xv[4 * c] * v.x + xv[4 * c + 1] * v.y +
                 xv[4 * c + 2] * v.z + xv[4 * c + 3] * v.w;
        }
#pragma unroll
        for (int s = 32; s > 0; s >>= 1) p += __shfl_xor(p, s, 64);
        logits[e] = p;
    }

    float scores[NE], sc[NE];
#pragma unroll
    for (int e = 0; e < NE; e++) {
        scores[e] = 1.f / (1.f + __expf(-logits[e]));
        sc[e] = scores[e] + eb[e];
    }

    // group score = sum of top-2 within each group of 4
    float gs[4];
#pragma unroll
    for (int g = 0; g < 4; g++) {
        float a = sc[4 * g], b = sc[4 * g + 1], c = sc[4 * g + 2], d = sc[4 * g + 3];
        float h1 = fmaxf(a, b), l1 = fminf(a, b);
        float h2 = fmaxf(c, d), l2 = fminf(c, d);
        gs[g] = fmaxf(h1, h2) + fmaxf(fminf(h1, h2), fmaxf(l1, l2));
    }
    // top-2 groups, lowest index wins ties (jax strict-> keeps first)
    int g0 = 0; float b0 = gs[0];
#pragma unroll
    for (int g = 1; g < 4; g++) if (gs[g] > b0) { b0 = gs[g]; g0 = g; }
    int g1 = -1; float b1 = -1e30f;
#pragma unroll
    for (int g = 0; g < 4; g++) if (g != g0 && gs[g] > b1) { b1 = gs[g]; g1 = g; }

    // top-4 experts within allowed groups
    int taken = 0;
    int bid[TOPK]; float bsc[TOPK]; float wsum = 0.f;
#pragma unroll
    for (int k = 0; k < TOPK; k++) {
        float bv = -1e30f; int bi = 0; float bs = 0.f;
#pragma unroll
        for (int e = 0; e < NE; e++) {
            int grp = e >> 2;
            bool ok = ((grp == g0) || (grp == g1)) && !((taken >> e) & 1);
            if (ok && sc[e] > bv) { bv = sc[e]; bi = e; bs = scores[e]; }
        }
        taken |= (1 << bi);
        bid[k] = bi; bsc[k] = bs; wsum += bs;
    }
    if (lane == 0) {
        float inv = 1.0f / (wsum + 1e-20f);
#pragma unroll
        for (int k = 0; k < TOPK; k++) {
            tk_idx[wid * TOPK + k] = bid[k];
            tk_w[wid * TOPK + k]   = bsc[k] * inv;
        }
    }
}

// ---------------- kernel 2: per-expert token lists ----------------
__global__ __launch_bounds__(256) void assign_k(
        const int* __restrict__ tk_idx, const float* __restrict__ tk_w,
        int* __restrict__ counts, int* __restrict__ tok_list,
        float* __restrict__ w_list) {
    int p = blockIdx.x * 256 + threadIdx.x;   // pair id < T_TOK*TOPK
    int e = tk_idx[p];
    float w = tk_w[p];
    int slot = atomicAdd(&counts[e], 1);
    tok_list[e * T_TOK + slot] = p >> 2;
    w_list[e * T_TOK + slot]  = w;
}

// ---------------- kernel 3: fused expert MLP ----------------
// grid (64 tiles, 16 experts), block 256 (4 waves). fp32 weights/activations
// converted to bf16 on the fly for 16x16x32 bf16 MFMA; fp32 accumulate;
// epilogue scales by routing weight and atomicAdds fp32 into out.
__global__ __launch_bounds__(256) void moe_k(
        const float* __restrict__ x,
        const float* __restrict__ gate_proj,
        const float* __restrict__ up_proj,
        const float* __restrict__ down_proj,
        const int* __restrict__ counts,
        const int* __restrict__ tok_list,
        const float* __restrict__ w_list,
        float* __restrict__ out) {
    __shared__ short xs[TM][128 + 8];   // X K-panel, bf16
    __shared__ short as_[TM][ID + 8];   // act tile, bf16
    __shared__ int   tok_s[TM];
    __shared__ float w_s[TM];

    int e = blockIdx.y;
    int cnt = counts[e];
    int base = blockIdx.x * TM;
    if (base >= cnt) return;

    int tid = threadIdx.x;
    if (tid < TM) {
        int s = base + tid;
        if (s < cnt) {
            tok_s[tid] = tok_list[e * T_TOK + s];
            w_s[tid]   = w_list[e * T_TOK + s];
        } else {
            tok_s[tid] = 0;
            w_s[tid]   = 0.f;   // padded slot contributes nothing
        }
    }
    __syncthreads();

    int wv = tid >> 6, lane = tid & 63;
    int qd = lane >> 4, l16 = lane & 15;
    int nb1 = wv * 128;                       // wave's N-range in GEMM1

    const float* gp = gate_proj + (size_t)e * ID * HD;
    const float* up = up_proj   + (size_t)e * ID * HD;

    f32x4 accg[2][8] = {};
    f32x4 accu[2][8] = {};

    for (int kp = 0; kp < HD; kp += 128) {
        __syncthreads();
        // stage X panel: 32 rows x 128 fp32 -> bf16 (512 chunks of 8)
#pragma unroll
        for (int c = 0; c < 2; c++) {
            int idx = c * 256 + tid;               // < 512
            int r = idx >> 4, col = (idx & 15) * 8;
            const float* src = x + (size_t)tok_s[r] * HD + kp + col;
            float4 a = *(const float4*)src;
            float4 b = *(const float4*)(src + 4);
            union { uint4 q; unsigned u[4]; } w;
            w.u[0] = pk2(a.x, a.y); w.u[1] = pk2(a.z, a.w);
            w.u[2] = pk2(b.x, b.y); w.u[3] = pk2(b.z, b.w);
            *(uint4*)(&xs[r][col]) = w.q;
        }
        __syncthreads();
#pragma unroll
        for (int k4 = 0; k4 < 4; k4++) {
            int kk = k4 * 32;
            bf16x8 a0 = *(const bf16x8*)(&xs[l16][kk + qd * 8]);
            bf16x8 a1 = *(const bf16x8*)(&xs[16 + l16][kk + qd * 8]);
#pragma unroll
            for (int n = 0; n < 8; n++) {
                size_t off = (size_t)(nb1 + n * 16 + l16) * HD + kp + kk + qd * 8;
                bf16x8 bg = cvt8(gp + off);
                bf16x8 bu = cvt8(up + off);
                accg[0][n] = MFMA_BF16(a0, bg, accg[0][n], 0, 0, 0);
                accg[1][n] = MFMA_BF16(a1, bg, accg[1][n], 0, 0, 0);
                accu[0][n] = MFMA_BF16(a0, bu, accu[0][n], 0, 0, 0);
                accu[1][n] = MFMA_BF16(a1, bu, accu[1][n], 0, 0, 0);
            }
        }
    }

    // act = silu(g)*u -> bf16 LDS (C/D layout: row = qd*4+r, col = l16)
    __syncthreads();
#pragma unroll
    for (int ms = 0; ms < 2; ms++)
#pragma unroll
        for (int n = 0; n < 8; n++)
#pragma unroll
            for (int r = 0; r < 4; r++) {
                float g = accg[ms][n][r], u = accu[ms][n][r];
                float a = g / (1.f + __expf(-g)) * u;
                as_[ms * 16 + qd * 4 + r][nb1 + n * 16 + l16] = f2bf(a);
            }
    __syncthreads();

    // GEMM2: out[m][h] = sum_i act[m][i] * down[h][i]
    const float* dp = down_proj + (size_t)e * HD * ID;
#pragma unroll 1
    for (int n2 = 0; n2 < 2; n2++) {
        int nb2 = wv * 256 + n2 * 128;
        f32x4 acc2[2][8] = {};
        for (int kk = 0; kk < ID; kk += 32) {
            bf16x8 a0 = *(const bf16x8*)(&as_[l16][kk + qd * 8]);
            bf16x8 a1 = *(const bf16x8*)(&as_[16 + l16][kk + qd * 8]);
#pragma unroll
            for (int n = 0; n < 8; n++) {
                size_t off = (size_t)(nb2 + n * 16 + l16) * ID + kk + qd * 8;
                bf16x8 bd = cvt8(dp + off);
                acc2[0][n] = MFMA_BF16(a0, bd, acc2[0][n], 0, 0, 0);
                acc2[1][n] = MFMA_BF16(a1, bd, acc2[1][n], 0, 0, 0);
            }
        }
#pragma unroll
        for (int ms = 0; ms < 2; ms++)
#pragma unroll
            for (int n = 0; n < 8; n++)
#pragma unroll
                for (int r = 0; r < 4; r++) {
                    int m = ms * 16 + qd * 4 + r;
                    float v = acc2[ms][n][r] * w_s[m];
                    atomicAdd(&out[(size_t)tok_s[m] * HD + nb2 + n * 16 + l16], v);
                }
    }
}

// ---------------- launch ----------------
extern "C" void kernel_launch(void* const* d_in, const int* in_sizes, int n_in,
                              void* d_out, int out_size, void* d_ws, size_t ws_size,
                              hipStream_t stream) {
    const float* x  = (const float*)d_in[0];   // hidden_states [T,H]
    const float* gw = (const float*)d_in[1];   // gate_weight  [E,H]
    const float* eb = (const float*)d_in[2];   // e_bias       [E]
    const float* gp = (const float*)d_in[3];   // gate_proj [E,I,H]
    const float* up = (const float*)d_in[4];   // up_proj   [E,I,H]
    const float* dp = (const float*)d_in[5];   // down_proj [E,H,I]

    char* wsb = (char*)d_ws;
    int* counts   = (int*)wsb;                        // 16
    int* tok_list = counts + NE;                      // E*T
    float* w_list = (float*)(tok_list + NE * T_TOK);  // E*T
    int* tk_idx   = (int*)(w_list + NE * T_TOK);      // T*4
    float* tk_w   = (float*)(tk_idx + T_TOK * TOPK);  // T*4

    hipMemsetAsync(counts, 0, NE * sizeof(int), stream);
    hipMemsetAsync(d_out, 0, (size_t)out_size * sizeof(float), stream);

    router_k<<<T_TOK / 4, 256, 0, stream>>>(x, gw, eb, tk_idx, tk_w);
    assign_k<<<T_TOK * TOPK / 256, 256, 0, stream>>>(tk_idx, tk_w, counts,
                                                     tok_list, w_list);
    moe_k<<<dim3(T_TOK / TM, NE), 256, 0, stream>>>(x, gp, up, dp, counts,
                                                    tok_list, w_list,
                                                    (float*)d_out);
}

// Round 3
// 583.467 us; speedup vs baseline: 1.4863x; 1.4863x over previous
//
#include <hip/hip_runtime.h>
#include <hip/hip_bf16.h>

// ---------------- types / helpers ----------------
typedef __attribute__((ext_vector_type(8))) short bf16x8;
typedef __attribute__((ext_vector_type(4))) float f32x4;

#define T_TOK 2048
#define HD 1024
#define ID 512
#define NE 16
#define TOPK 4
#define TM 32   // tokens per expert tile

// pack two fp32 -> two bf16 (truncate): one v_perm_b32
__device__ __forceinline__ unsigned pk2(float a, float b) {
    return __builtin_amdgcn_perm(__float_as_uint(b), __float_as_uint(a),
                                 0x07060302u);
}
// load 8 fp32, convert to bf16x8 (two dwordx4 + 4 v_perm)
__device__ __forceinline__ bf16x8 cvt8(const float* __restrict__ p) {
    float4 a = *(const float4*)p;
    float4 b = *(const float4*)(p + 4);
    union { bf16x8 v; unsigned u[4]; } r;
    r.u[0] = pk2(a.x, a.y); r.u[1] = pk2(a.z, a.w);
    r.u[2] = pk2(b.x, b.y); r.u[3] = pk2(b.z, b.w);
    return r.v;
}
__device__ __forceinline__ short f2bf(float f) {  // RTNE
    unsigned u = __float_as_uint(f);
    return (short)((u + 0x7fffu + ((u >> 16) & 1u)) >> 16);
}

#define MFMA_BF16 __builtin_amdgcn_mfma_f32_16x16x32_bf16

// ---------------- kernel 1: router ----------------
__global__ __launch_bounds__(256) void router_k(
        const float* __restrict__ x, const float* __restrict__ gw,
        const float* __restrict__ eb,
        int* __restrict__ tk_idx, float* __restrict__ tk_w) {
    int wid  = (blockIdx.x * 256 + threadIdx.x) >> 6;   // token id
    int lane = threadIdx.x & 63;

    const float* xr = x + (size_t)wid * HD + lane * 16;
    float xv[16];
#pragma unroll
    for (int c = 0; c < 4; c++) {
        float4 v = *(const float4*)(xr + c * 4);
        xv[4 * c] = v.x; xv[4 * c + 1] = v.y; xv[4 * c + 2] = v.z; xv[4 * c + 3] = v.w;
    }

    float logits[NE];
#pragma unroll
    for (int e = 0; e < NE; e++) {
        const float* gr = gw + e * HD + lane * 16;
        float p = 0.f;
#pragma unroll
        for (int c = 0; c < 4; c++) {
            float4 v = *(const float4*)(gr + c * 4);
            p += xv[4 * c] * v.x + xv[4 * c + 1] * v.y +
                 xv[4 * c + 2] * v.z + xv[4 * c + 3] * v.w;
        }
#pragma unroll
        for (int s = 32; s > 0; s >>= 1) p += __shfl_xor(p, s, 64);
        logits[e] = p;
    }

    float scores[NE], sc[NE];
#pragma unroll
    for (int e = 0; e < NE; e++) {
        scores[e] = 1.f / (1.f + __expf(-logits[e]));
        sc[e] = scores[e] + eb[e];
    }

    float gs[4];
#pragma unroll
    for (int g = 0; g < 4; g++) {
        float a = sc[4 * g], b = sc[4 * g + 1], c = sc[4 * g + 2], d = sc[4 * g + 3];
        float h1 = fmaxf(a, b), l1 = fminf(a, b);
        float h2 = fmaxf(c, d), l2 = fminf(c, d);
        gs[g] = fmaxf(h1, h2) + fmaxf(fminf(h1, h2), fmaxf(l1, l2));
    }
    int g0 = 0; float b0 = gs[0];
#pragma unroll
    for (int g = 1; g < 4; g++) if (gs[g] > b0) { b0 = gs[g]; g0 = g; }
    int g1 = -1; float b1 = -1e30f;
#pragma unroll
    for (int g = 0; g < 4; g++) if (g != g0 && gs[g] > b1) { b1 = gs[g]; g1 = g; }

    int taken = 0;
    int bid[TOPK]; float bsc[TOPK]; float wsum = 0.f;
#pragma unroll
    for (int k = 0; k < TOPK; k++) {
        float bv = -1e30f; int bi = 0; float bs = 0.f;
#pragma unroll
        for (int e = 0; e < NE; e++) {
            int grp = e >> 2;
            bool ok = ((grp == g0) || (grp == g1)) && !((taken >> e) & 1);
            if (ok && sc[e] > bv) { bv = sc[e]; bi = e; bs = scores[e]; }
        }
        taken |= (1 << bi);
        bid[k] = bi; bsc[k] = bs; wsum += bs;
    }
    if (lane == 0) {
        float inv = 1.0f / (wsum + 1e-20f);
#pragma unroll
        for (int k = 0; k < TOPK; k++) {
            tk_idx[wid * TOPK + k] = bid[k];
            tk_w[wid * TOPK + k]   = bsc[k] * inv;
        }
    }
}

// ---------------- kernel 2: per-expert token lists ----------------
__global__ __launch_bounds__(256) void assign_k(
        const int* __restrict__ tk_idx, const float* __restrict__ tk_w,
        int* __restrict__ counts, int* __restrict__ tok_list,
        float* __restrict__ w_list) {
    int p = blockIdx.x * 256 + threadIdx.x;   // pair id < T_TOK*TOPK
    int e = tk_idx[p];
    float w = tk_w[p];
    int slot = atomicAdd(&counts[e], 1);
    tok_list[e * T_TOK + slot] = p >> 2;
    w_list[e * T_TOK + slot]  = w;
}

// ---------------- kernel 2b: prefix offsets ----------------
__global__ void offs_k(const int* __restrict__ counts, int* __restrict__ offs) {
    if (threadIdx.x == 0) {
        int a = 0;
#pragma unroll
        for (int e = 0; e < NE; e++) { offs[e] = a; a += counts[e]; }
    }
}

// ---------------- kernel 3: GEMM1 (x @ gate/up^T, silu*up -> act) ----------
// grid (m_tiles=64, n_slices=4, experts=16), block 256 = 4 waves.
// block tile M=32 x N=128; wave tile 32x32 (2m x 2n frags).
__global__ __launch_bounds__(256) void gemm1_k(
        const float* __restrict__ x,
        const float* __restrict__ gate_proj,
        const float* __restrict__ up_proj,
        const int* __restrict__ counts,
        const int* __restrict__ offs,
        const int* __restrict__ tok_list,
        short* __restrict__ act) {
    __shared__ short xs[TM][128 + 8];
    __shared__ int   tok_s[TM];

    int e = blockIdx.z;
    int cnt = counts[e];
    int base = blockIdx.x * TM;
    if (base >= cnt) return;
    int arow0 = offs[e] + base;

    int tid = threadIdx.x;
    if (tid < TM) {
        int s = base + tid;
        tok_s[tid] = (s < cnt) ? tok_list[e * T_TOK + s] : tok_list[e * T_TOK];
    }
    __syncthreads();

    int wv = tid >> 6, lane = tid & 63;
    int qd = lane >> 4, l16 = lane & 15;
    int nb = blockIdx.y * 128 + wv * 32;      // this wave's N-range [nb,nb+32)

    const float* gp = gate_proj + (size_t)e * ID * HD;
    const float* up = up_proj   + (size_t)e * ID * HD;

    f32x4 accg[2][2] = {};
    f32x4 accu[2][2] = {};

    for (int kp = 0; kp < HD; kp += 128) {
        __syncthreads();
#pragma unroll
        for (int c = 0; c < 2; c++) {
            int idx = c * 256 + tid;               // < 512
            int r = idx >> 4, col = (idx & 15) * 8;
            const float* src = x + (size_t)tok_s[r] * HD + kp + col;
            float4 a = *(const float4*)src;
            float4 b = *(const float4*)(src + 4);
            union { uint4 q; unsigned u[4]; } w;
            w.u[0] = pk2(a.x, a.y); w.u[1] = pk2(a.z, a.w);
            w.u[2] = pk2(b.x, b.y); w.u[3] = pk2(b.z, b.w);
            *(uint4*)(&xs[r][col]) = w.q;
        }
        __syncthreads();
#pragma unroll
        for (int k4 = 0; k4 < 4; k4++) {
            int kk = k4 * 32;
            bf16x8 a0 = *(const bf16x8*)(&xs[l16][kk + qd * 8]);
            bf16x8 a1 = *(const bf16x8*)(&xs[16 + l16][kk + qd * 8]);
#pragma unroll
            for (int n = 0; n < 2; n++) {
                size_t off = (size_t)(nb + n * 16 + l16) * HD + kp + kk + qd * 8;
                bf16x8 bg = cvt8(gp + off);
                bf16x8 bu = cvt8(up + off);
                accg[0][n] = MFMA_BF16(a0, bg, accg[0][n], 0, 0, 0);
                accg[1][n] = MFMA_BF16(a1, bg, accg[1][n], 0, 0, 0);
                accu[0][n] = MFMA_BF16(a0, bu, accu[0][n], 0, 0, 0);
                accu[1][n] = MFMA_BF16(a1, bu, accu[1][n], 0, 0, 0);
            }
        }
    }

    // act = silu(g)*u -> bf16 global (row = arow0+m, col = nb+n*16+l16)
#pragma unroll
    for (int ms = 0; ms < 2; ms++)
#pragma unroll
        for (int n = 0; n < 2; n++)
#pragma unroll
            for (int r = 0; r < 4; r++) {
                int m = ms * 16 + qd * 4 + r;
                if (base + m < cnt) {
                    float g = accg[ms][n][r], u = accu[ms][n][r];
                    float a = g / (1.f + __expf(-g)) * u;
                    act[(size_t)(arow0 + m) * ID + nb + n * 16 + l16] = f2bf(a);
                }
            }
}

// ---------------- kernel 4: GEMM2 (act @ down^T, scale, scatter-add) ------
// grid (m_tiles=64, n_slices=8, experts=16), block 256 = 4 waves.
// block tile M=32 x N=128 over HD; K=512 staged from act.
__global__ __launch_bounds__(256) void gemm2_k(
        const short* __restrict__ act,
        const float* __restrict__ down_proj,
        const int* __restrict__ counts,
        const int* __restrict__ offs,
        const int* __restrict__ tok_list,
        const float* __restrict__ w_list,
        float* __restrict__ out) {
    __shared__ short as_[TM][ID + 8];
    __shared__ int   tok_s[TM];
    __shared__ float w_s[TM];

    int e = blockIdx.z;
    int cnt = counts[e];
    int base = blockIdx.x * TM;
    if (base >= cnt) return;
    int arow0 = offs[e] + base;

    int tid = threadIdx.x;
    if (tid < TM) {
        int s = base + tid;
        if (s < cnt) {
            tok_s[tid] = tok_list[e * T_TOK + s];
            w_s[tid]   = w_list[e * T_TOK + s];
        } else {
            tok_s[tid] = 0;
            w_s[tid]   = 0.f;   // padded: contributes nothing
        }
    }
    __syncthreads();

    // stage act tile: 32 rows x 512 bf16 (rows beyond cnt are stale/garbage
    // but finite; they get weight 0)
#pragma unroll
    for (int c = 0; c < 8; c++) {
        int idx = c * 256 + tid;               // < 2048
        int r = idx >> 6, col = (idx & 63) * 8;
        *(uint4*)(&as_[r][col]) =
            *(const uint4*)(act + (size_t)(arow0 + r) * ID + col);
    }
    __syncthreads();

    int wv = tid >> 6, lane = tid & 63;
    int qd = lane >> 4, l16 = lane & 15;
    int nb = blockIdx.y * 128 + wv * 32;      // this wave's H-range [nb,nb+32)

    const float* dp = down_proj + (size_t)e * HD * ID;
    f32x4 acc[2][2] = {};
    for (int kk = 0; kk < ID; kk += 32) {
        bf16x8 a0 = *(const bf16x8*)(&as_[l16][kk + qd * 8]);
        bf16x8 a1 = *(const bf16x8*)(&as_[16 + l16][kk + qd * 8]);
#pragma unroll
        for (int n = 0; n < 2; n++) {
            size_t off = (size_t)(nb + n * 16 + l16) * ID + kk + qd * 8;
            bf16x8 bd = cvt8(dp + off);
            acc[0][n] = MFMA_BF16(a0, bd, acc[0][n], 0, 0, 0);
            acc[1][n] = MFMA_BF16(a1, bd, acc[1][n], 0, 0, 0);
        }
    }
#pragma unroll
    for (int ms = 0; ms < 2; ms++)
#pragma unroll
        for (int n = 0; n < 2; n++)
#pragma unroll
            for (int r = 0; r < 4; r++) {
                int m = ms * 16 + qd * 4 + r;
                float v = acc[ms][n][r] * w_s[m];
                atomicAdd(&out[(size_t)tok_s[m] * HD + nb + n * 16 + l16], v);
            }
}

// ---------------- launch ----------------
extern "C" void kernel_launch(void* const* d_in, const int* in_sizes, int n_in,
                              void* d_out, int out_size, void* d_ws, size_t ws_size,
                              hipStream_t stream) {
    const float* x  = (const float*)d_in[0];   // hidden_states [T,H]
    const float* gw = (const float*)d_in[1];   // gate_weight  [E,H]
    const float* eb = (const float*)d_in[2];   // e_bias       [E]
    const float* gp = (const float*)d_in[3];   // gate_proj [E,I,H]
    const float* up = (const float*)d_in[4];   // up_proj   [E,I,H]
    const float* dp = (const float*)d_in[5];   // down_proj [E,H,I]

    char* wsb = (char*)d_ws;
    // act first (16B aligned): (T*TOPK + TM) rows x ID bf16
    short* act    = (short*)wsb;
    size_t act_sz = (size_t)(T_TOK * TOPK + TM) * ID * sizeof(short);
    int* counts   = (int*)(wsb + act_sz);             // 16
    int* offs     = counts + NE;                      // 16
    int* tok_list = offs + NE;                        // E*T
    float* w_list = (float*)(tok_list + NE * T_TOK);  // E*T
    int* tk_idx   = (int*)(w_list + NE * T_TOK);      // T*4
    float* tk_w   = (float*)(tk_idx + T_TOK * TOPK);  // T*4

    hipMemsetAsync(counts, 0, NE * sizeof(int), stream);
    hipMemsetAsync(d_out, 0, (size_t)out_size * sizeof(float), stream);

    router_k<<<T_TOK / 4, 256, 0, stream>>>(x, gw, eb, tk_idx, tk_w);
    assign_k<<<T_TOK * TOPK / 256, 256, 0, stream>>>(tk_idx, tk_w, counts,
                                                     tok_list, w_list);
    offs_k<<<1, 64, 0, stream>>>(counts, offs);
    gemm1_k<<<dim3(T_TOK / TM, 4, NE), 256, 0, stream>>>(
        x, gp, up, counts, offs, tok_list, act);
    gemm2_k<<<dim3(T_TOK / TM, 8, NE), 256, 0, stream>>>(
        act, dp, counts, offs, tok_list, w_list, (float*)d_out);
}

// Round 4
// 401.283 us; speedup vs baseline: 2.1610x; 1.4540x over previous
//
#include <hip/hip_runtime.h>
#include <hip/hip_bf16.h>

// ---------------- types / helpers ----------------
typedef __attribute__((ext_vector_type(8))) short bf16x8;
typedef __attribute__((ext_vector_type(4))) float f32x4;

#define T_TOK 2048
#define HD 1024
#define ID 512
#define NE 16
#define TOPK 4
#define BK 64            // K-panel depth (bf16)
#define WELEM (HD*ID*NE) // elems per weight tensor = 8388608

// pack two fp32 -> two bf16 (truncate): one v_perm_b32
__device__ __forceinline__ unsigned pk2(float a, float b) {
    return __builtin_amdgcn_perm(__float_as_uint(b), __float_as_uint(a),
                                 0x07060302u);
}
// load 8 fp32, convert to bf16x8
__device__ __forceinline__ bf16x8 cvt8(const float* __restrict__ p) {
    float4 a = *(const float4*)p;
    float4 b = *(const float4*)(p + 4);
    union { bf16x8 v; unsigned u[4]; } r;
    r.u[0] = pk2(a.x, a.y); r.u[1] = pk2(a.z, a.w);
    r.u[2] = pk2(b.x, b.y); r.u[3] = pk2(b.z, b.w);
    return r.v;
}
__device__ __forceinline__ short f2bf(float f) {  // RTNE
    unsigned u = __float_as_uint(f);
    return (short)((u + 0x7fffu + ((u >> 16) & 1u)) >> 16);
}

#define MFMA_BF16 __builtin_amdgcn_mfma_f32_16x16x32_bf16

// ---------------- kernel 0: fp32 -> bf16 weight convert ----------------
__global__ __launch_bounds__(256) void conv_k(const float* __restrict__ src,
                                              short* __restrict__ dst) {
    size_t i = ((size_t)blockIdx.x * 256 + threadIdx.x) * 8;
    union { bf16x8 v; uint4 q; } r;
    r.v = cvt8(src + i);
    *(uint4*)(dst + i) = r.q;
}

// ---------------- kernel 1: router (+ x -> bf16) ----------------
__global__ __launch_bounds__(256) void router_k(
        const float* __restrict__ x, const float* __restrict__ gw,
        const float* __restrict__ eb,
        int* __restrict__ tk_idx, float* __restrict__ tk_w,
        short* __restrict__ xb) {
    int wid  = (blockIdx.x * 256 + threadIdx.x) >> 6;   // token id
    int lane = threadIdx.x & 63;

    const float* xr = x + (size_t)wid * HD + lane * 16;
    float xv[16];
#pragma unroll
    for (int c = 0; c < 4; c++) {
        float4 v = *(const float4*)(xr + c * 4);
        xv[4 * c] = v.x; xv[4 * c + 1] = v.y; xv[4 * c + 2] = v.z; xv[4 * c + 3] = v.w;
    }
    // write bf16 copy of x (coalesced 32B/lane)
    {
        union { uint4 q; unsigned u[4]; } w0, w1;
        w0.u[0] = pk2(xv[0], xv[1]);  w0.u[1] = pk2(xv[2], xv[3]);
        w0.u[2] = pk2(xv[4], xv[5]);  w0.u[3] = pk2(xv[6], xv[7]);
        w1.u[0] = pk2(xv[8], xv[9]);  w1.u[1] = pk2(xv[10], xv[11]);
        w1.u[2] = pk2(xv[12], xv[13]); w1.u[3] = pk2(xv[14], xv[15]);
        short* d = xb + ((size_t)wid << 10) + lane * 16;
        *(uint4*)d = w0.q;
        *(uint4*)(d + 8) = w1.q;
    }

    float logits[NE];
#pragma unroll
    for (int e = 0; e < NE; e++) {
        const float* gr = gw + e * HD + lane * 16;
        float p = 0.f;
#pragma unroll
        for (int c = 0; c < 4; c++) {
            float4 v = *(const float4*)(gr + c * 4);
            p += xv[4 * c] * v.x + xv[4 * c + 1] * v.y +
                 xv[4 * c + 2] * v.z + xv[4 * c + 3] * v.w;
        }
#pragma unroll
        for (int s = 32; s > 0; s >>= 1) p += __shfl_xor(p, s, 64);
        logits[e] = p;
    }

    float scores[NE], sc[NE];
#pragma unroll
    for (int e = 0; e < NE; e++) {
        scores[e] = 1.f / (1.f + __expf(-logits[e]));
        sc[e] = scores[e] + eb[e];
    }

    float gs[4];
#pragma unroll
    for (int g = 0; g < 4; g++) {
        float a = sc[4 * g], b = sc[4 * g + 1], c = sc[4 * g + 2], d = sc[4 * g + 3];
        float h1 = fmaxf(a, b), l1 = fminf(a, b);
        float h2 = fmaxf(c, d), l2 = fminf(c, d);
        gs[g] = fmaxf(h1, h2) + fmaxf(fminf(h1, h2), fmaxf(l1, l2));
    }
    int g0 = 0; float b0 = gs[0];
#pragma unroll
    for (int g = 1; g < 4; g++) if (gs[g] > b0) { b0 = gs[g]; g0 = g; }
    int g1 = -1; float b1 = -1e30f;
#pragma unroll
    for (int g = 0; g < 4; g++) if (g != g0 && gs[g] > b1) { b1 = gs[g]; g1 = g; }

    int taken = 0;
    int bid[TOPK]; float bsc[TOPK]; float wsum = 0.f;
#pragma unroll
    for (int k = 0; k < TOPK; k++) {
        float bv = -1e30f; int bi = 0; float bs = 0.f;
#pragma unroll
        for (int e = 0; e < NE; e++) {
            int grp = e >> 2;
            bool ok = ((grp == g0) || (grp == g1)) && !((taken >> e) & 1);
            if (ok && sc[e] > bv) { bv = sc[e]; bi = e; bs = scores[e]; }
        }
        taken |= (1 << bi);
        bid[k] = bi; bsc[k] = bs; wsum += bs;
    }
    if (lane == 0) {
        float inv = 1.0f / (wsum + 1e-20f);
#pragma unroll
        for (int k = 0; k < TOPK; k++) {
            tk_idx[wid * TOPK + k] = bid[k];
            tk_w[wid * TOPK + k]   = bsc[k] * inv;
        }
    }
}

// ---------------- kernel 2: per-expert token lists ----------------
__global__ __launch_bounds__(256) void assign_k(
        const int* __restrict__ tk_idx, const float* __restrict__ tk_w,
        int* __restrict__ counts, int* __restrict__ tok_list,
        float* __restrict__ w_list) {
    int p = blockIdx.x * 256 + threadIdx.x;   // pair id < T_TOK*TOPK
    int e = tk_idx[p];
    float w = tk_w[p];
    int slot = atomicAdd(&counts[e], 1);
    tok_list[e * T_TOK + slot] = p >> 2;
    w_list[e * T_TOK + slot]  = w;
}

__global__ void offs_k(const int* __restrict__ counts, int* __restrict__ offs) {
    if (threadIdx.x == 0) {
        int a = 0;
#pragma unroll
        for (int e = 0; e < NE; e++) { offs[e] = a; a += counts[e]; }
    }
}

// ---------------- kernel 3: GEMM1 -----------------------------------------
// block tile M=128 tokens x N=64 inter-cols (gate AND up), K=1024, BK=64.
// 4 waves in 2x2, wave tile 64x32. A(x) and B(gate,up) tiles staged in LDS
// (bf16, coalesced), XOR-swizzled chunks -> conflict-free ds_read_b128.
__global__ __launch_bounds__(256) void gemm1_k(
        const short* __restrict__ xb,
        const short* __restrict__ gpb,
        const short* __restrict__ upb,
        const int* __restrict__ counts,
        const int* __restrict__ offs,
        const int* __restrict__ tok_list,
        short* __restrict__ act) {
    __shared__ short xs[128 * BK];
    __shared__ short gs[64 * BK];
    __shared__ short us[64 * BK];
    __shared__ int   tok_s[128];

    int e = blockIdx.z;
    int cnt = counts[e];
    int base = blockIdx.x * 128;
    if (base >= cnt) return;
    int arow0 = offs[e] + base;

    int tid = threadIdx.x;
    if (tid < 128) {
        int s = base + tid;
        tok_s[tid] = (s < cnt) ? tok_list[e * T_TOK + s] : tok_list[e * T_TOK];
    }

    int wv = tid >> 6, lane = tid & 63;
    int qd = lane >> 4, l16 = lane & 15;
    int wm = (wv >> 1) * 64, wn = (wv & 1) * 32;
    int nb0 = blockIdx.y * 64;
    const short* gp = gpb + (size_t)e * ID * HD + (size_t)nb0 * HD;
    const short* up = upb + (size_t)e * ID * HD + (size_t)nb0 * HD;

    f32x4 accg[4][2] = {};
    f32x4 accu[4][2] = {};
    __syncthreads();

    for (int kp = 0; kp < HD; kp += BK) {
        // stage x tile: 128 rows x 8 chunks of 16B
#pragma unroll
        for (int i = 0; i < 4; i++) {
            int idx = i * 256 + tid;
            int r = idx >> 3, c = idx & 7;
            *(uint4*)&xs[(r << 6) + (((c ^ r) & 7) << 3)] =
                *(const uint4*)(xb + ((size_t)tok_s[r] << 10) + kp + (c << 3));
        }
        // stage gate/up tiles: 64 rows x 8 chunks
#pragma unroll
        for (int i = 0; i < 2; i++) {
            int idx = i * 256 + tid;
            int r = idx >> 3, c = idx & 7;
            size_t go = (size_t)r * HD + kp + (c << 3);
            int lo = (r << 6) + (((c ^ r) & 7) << 3);
            *(uint4*)&gs[lo] = *(const uint4*)(gp + go);
            *(uint4*)&us[lo] = *(const uint4*)(up + go);
        }
        __syncthreads();
#pragma unroll
        for (int ks = 0; ks < 2; ks++) {
            int cb = ks * 4 + qd;
            bf16x8 af[4], bg[2], bu[2];
#pragma unroll
            for (int i = 0; i < 4; i++) {
                int r = wm + i * 16 + l16;
                af[i] = *(const bf16x8*)&xs[(r << 6) + (((cb ^ r) & 7) << 3)];
            }
#pragma unroll
            for (int j = 0; j < 2; j++) {
                int r = wn + j * 16 + l16;
                int lo = (r << 6) + (((cb ^ r) & 7) << 3);
                bg[j] = *(const bf16x8*)&gs[lo];
                bu[j] = *(const bf16x8*)&us[lo];
            }
#pragma unroll
            for (int i = 0; i < 4; i++)
#pragma unroll
                for (int j = 0; j < 2; j++) {
                    accg[i][j] = MFMA_BF16(af[i], bg[j], accg[i][j], 0, 0, 0);
                    accu[i][j] = MFMA_BF16(af[i], bu[j], accu[i][j], 0, 0, 0);
                }
        }
        __syncthreads();
    }

    // epilogue: silu(g)*u -> bf16 act rows
#pragma unroll
    for (int i = 0; i < 4; i++)
#pragma unroll
        for (int j = 0; j < 2; j++)
#pragma unroll
            for (int r = 0; r < 4; r++) {
                int m = wm + i * 16 + qd * 4 + r;
                if (base + m < cnt) {
                    float g = accg[i][j][r], u = accu[i][j][r];
                    float a = g / (1.f + __expf(-g)) * u;
                    act[(size_t)(arow0 + m) * ID + nb0 + wn + j * 16 + l16] = f2bf(a);
                }
            }
}

// ---------------- kernel 4: GEMM2 -----------------------------------------
// block tile M=128 act-rows x N=128 hidden-cols, K=512, BK=64.
// wave tile 64x64 (2x2 waves). Scatter-add fp32 into out.
__global__ __launch_bounds__(256) void gemm2_k(
        const short* __restrict__ act,
        const short* __restrict__ dpb,
        const int* __restrict__ counts,
        const int* __restrict__ offs,
        const int* __restrict__ tok_list,
        const float* __restrict__ w_list,
        float* __restrict__ out) {
    __shared__ short as_[128 * BK];
    __shared__ short ds_[128 * BK];
    __shared__ int   tok_s[128];
    __shared__ float w_s[128];

    int e = blockIdx.z;
    int cnt = counts[e];
    int base = blockIdx.x * 128;
    if (base >= cnt) return;
    int arow0 = offs[e] + base;

    int tid = threadIdx.x;
    if (tid < 128) {
        int s = base + tid;
        if (s < cnt) {
            tok_s[tid] = tok_list[e * T_TOK + s];
            w_s[tid]   = w_list[e * T_TOK + s];
        } else {
            tok_s[tid] = 0;
            w_s[tid]   = 0.f;   // padded rows contribute nothing
        }
    }

    int wv = tid >> 6, lane = tid & 63;
    int qd = lane >> 4, l16 = lane & 15;
    int wm = (wv >> 1) * 64, wn = (wv & 1) * 64;
    int hb0 = blockIdx.y * 128;
    const short* dp = dpb + (size_t)e * HD * ID + (size_t)hb0 * ID;

    f32x4 acc[4][4] = {};
    __syncthreads();

    for (int kp = 0; kp < ID; kp += BK) {
#pragma unroll
        for (int i = 0; i < 4; i++) {
            int idx = i * 256 + tid;
            int r = idx >> 3, c = idx & 7;
            int lo = (r << 6) + (((c ^ r) & 7) << 3);
            *(uint4*)&as_[lo] =
                *(const uint4*)(act + (size_t)(arow0 + r) * ID + kp + (c << 3));
            *(uint4*)&ds_[lo] =
                *(const uint4*)(dp + (size_t)r * ID + kp + (c << 3));
        }
        __syncthreads();
#pragma unroll
        for (int ks = 0; ks < 2; ks++) {
            int cb = ks * 4 + qd;
            bf16x8 af[4], bd[4];
#pragma unroll
            for (int i = 0; i < 4; i++) {
                int r = wm + i * 16 + l16;
                af[i] = *(const bf16x8*)&as_[(r << 6) + (((cb ^ r) & 7) << 3)];
                int r2 = wn + i * 16 + l16;
                bd[i] = *(const bf16x8*)&ds_[(r2 << 6) + (((cb ^ r2) & 7) << 3)];
            }
#pragma unroll
            for (int i = 0; i < 4; i++)
#pragma unroll
                for (int j = 0; j < 4; j++)
                    acc[i][j] = MFMA_BF16(af[i], bd[j], acc[i][j], 0, 0, 0);
        }
        __syncthreads();
    }

#pragma unroll
    for (int i = 0; i < 4; i++)
#pragma unroll
        for (int j = 0; j < 4; j++)
#pragma unroll
            for (int r = 0; r < 4; r++) {
                int m = wm + i * 16 + qd * 4 + r;
                float v = acc[i][j][r] * w_s[m];
                atomicAdd(&out[(size_t)tok_s[m] * HD + hb0 + wn + j * 16 + l16], v);
            }
}

// ---------------- launch ----------------
extern "C" void kernel_launch(void* const* d_in, const int* in_sizes, int n_in,
                              void* d_out, int out_size, void* d_ws, size_t ws_size,
                              hipStream_t stream) {
    const float* x  = (const float*)d_in[0];   // hidden_states [T,H]
    const float* gw = (const float*)d_in[1];   // gate_weight  [E,H]
    const float* eb = (const float*)d_in[2];   // e_bias       [E]
    const float* gp = (const float*)d_in[3];   // gate_proj [E,I,H]
    const float* up = (const float*)d_in[4];   // up_proj   [E,I,H]
    const float* dp = (const float*)d_in[5];   // down_proj [E,H,I]

    short* gpb = (short*)d_ws;                  // bf16 weights: 3 x 16 MB
    short* upb = gpb + WELEM;
    short* dpb = upb + WELEM;
    short* xb  = dpb + WELEM;                   // x bf16: 2048x1024
    short* act = xb + (size_t)T_TOK * HD;       // (8192+128) x 512 bf16
    int* counts   = (int*)(act + (size_t)(T_TOK * TOPK + 128) * ID);
    int* offs     = counts + NE;
    int* tok_list = offs + NE;                        // E*T
    float* w_list = (float*)(tok_list + NE * T_TOK);  // E*T
    int* tk_idx   = (int*)(w_list + NE * T_TOK);      // T*4
    float* tk_w   = (float*)(tk_idx + T_TOK * TOPK);  // T*4

    hipMemsetAsync(counts, 0, NE * sizeof(int), stream);
    hipMemsetAsync(d_out, 0, (size_t)out_size * sizeof(float), stream);

    conv_k<<<WELEM / 8 / 256, 256, 0, stream>>>(gp, gpb);
    conv_k<<<WELEM / 8 / 256, 256, 0, stream>>>(up, upb);
    conv_k<<<WELEM / 8 / 256, 256, 0, stream>>>(dp, dpb);
    router_k<<<T_TOK / 4, 256, 0, stream>>>(x, gw, eb, tk_idx, tk_w, xb);
    assign_k<<<T_TOK * TOPK / 256, 256, 0, stream>>>(tk_idx, tk_w, counts,
                                                     tok_list, w_list);
    offs_k<<<1, 64, 0, stream>>>(counts, offs);
    gemm1_k<<<dim3(T_TOK / 128, ID / 64, NE), 256, 0, stream>>>(
        xb, gpb, upb, counts, offs, tok_list, act);
    gemm2_k<<<dim3(T_TOK / 128, HD / 128, NE), 256, 0, stream>>>(
        act, dpb, counts, offs, tok_list, w_list, (float*)d_out);
}